// Round 11
// baseline (588.695 us; speedup 1.0000x reference)
//
#include <hip/hip_runtime.h>
#include <hip/hip_bf16.h>
#include <hip/hip_cooperative_groups.h>

namespace cg = cooperative_groups;

// out[4096,1000] = core[4096,4096] @ weights[1000,4096]^T, fp32.
// R11: single cooperative fused kernel (convert -> gridsync -> f16 GEMM
//      [R7 K-loop, KSPLIT=2, f16 partials] -> gridsync -> reduce).
//      Probes whether the constant ~78us dispatch-gap is per-dispatch
//      (fusion wins) or fixed harness reset (neutral). Runtime fallback to
//      the proven R7 3-kernel path if coop launch fails.

#define M_DIM 4096
#define K_DIM 4096
#define N_CLS 1000
#define N_PAD 1024

#define BM 128
#define BN 128
#define BK 32
#define KSPLIT 2
#define GEMM_BLOCKS 512   // (N_PAD/BN) * (M_DIM/BM) * KSPLIT
#define COOP_BLOCKS 1024  // 4 blocks/CU co-resident

typedef _Float16 f16x8 __attribute__((ext_vector_type(8)));
typedef _Float16 f16x4 __attribute__((ext_vector_type(4)));
typedef float f32x4 __attribute__((ext_vector_type(4)));

#define A_ELEMS ((size_t)M_DIM * K_DIM)    // 16,777,216
#define W_SRC   ((size_t)N_CLS * K_DIM)    //  4,096,000
#define W_ELEMS ((size_t)N_PAD * K_DIM)    //  4,194,304
#define P_ELEMS ((size_t)KSPLIT * M_DIM * N_PAD)

// ---------- async global->LDS, width 16 (literal) ----------
__device__ inline void load_lds16(const _Float16* g, _Float16* l) {
    __builtin_amdgcn_global_load_lds(
        (const __attribute__((address_space(1))) unsigned int*)(const void*)g,
        (__attribute__((address_space(3))) unsigned int*)(void*)l, 16, 0, 0);
}

// ---------- shared device bodies (used by fused and fallback paths) ----------
__device__ inline void convert_body(const float* __restrict__ core,
                                    const float* __restrict__ wts,
                                    _Float16* __restrict__ A16,
                                    _Float16* __restrict__ W16,
                                    int gsize, int gidx) {
    const int na8 = (int)(A_ELEMS / 8);
    const int nw8 = (int)(W_ELEMS / 8);
    const int total = na8 + nw8;
    for (int i = gidx; i < total; i += gsize) {
        const float* src;
        _Float16* dst;
        bool valid;
        if (i < na8) {
            src = core + (size_t)i * 8;
            dst = A16 + (size_t)i * 8;
            valid = true;
        } else {
            int j = i - na8;
            src = wts + (size_t)j * 8;
            dst = W16 + (size_t)j * 8;
            valid = ((size_t)j * 8 < W_SRC);
        }
        float f[8] = {0, 0, 0, 0, 0, 0, 0, 0};
        if (valid) {
            float4 v0 = ((const float4*)src)[0];
            float4 v1 = ((const float4*)src)[1];
            f[0] = v0.x; f[1] = v0.y; f[2] = v0.z; f[3] = v0.w;
            f[4] = v1.x; f[5] = v1.y; f[6] = v1.z; f[7] = v1.w;
        }
        f16x8 h;
#pragma unroll
        for (int j = 0; j < 8; ++j) h[j] = (_Float16)f[j];   // RNE
        *(f16x8*)dst = h;
    }
}

// GEMM body: R7 K-loop (128x128, BK=32, dbuf 2ph, XOR-swizzled LDS via
// pre-swizzled source, 0 conflicts measured R3/R6/R7). bid in [0, 512).
__device__ inline void gemm_body(const _Float16* __restrict__ A16,
                                 const _Float16* __restrict__ W16,
                                 _Float16* __restrict__ P,
                                 _Float16* sAB,   // [2][BM*64]
                                 int bid) {
    const int tid  = threadIdx.x;
    const int lane = tid & 63;
    const int wid  = tid >> 6;
    const int wr   = wid >> 1;
    const int wc   = wid & 1;

    int swz = (bid & 7) * 64 + (bid >> 3);
    const int colb = swz & 7;
    const int ks   = (swz >> 3) & 1;
    const int rowb = swz >> 4;
    const int brow = rowb * BM;
    const int bcol = colb * BN;
    const int kbeg = ks * (K_DIM / KSPLIT);
    const int NT   = (K_DIM / KSPLIT) / BK;   // 64

    const _Float16* src[4];
    int dstOff[4];
#pragma unroll
    for (int i = 0; i < 4; ++i) {
        int s = tid + 256 * i;
        int r = s >> 3;
        int clog = (s & 7) ^ (r & 7);
        dstOff[i] = s * 8;
        if (clog < 4)
            src[i] = A16 + (size_t)(brow + r) * K_DIM + kbeg + clog * 8;
        else
            src[i] = W16 + (size_t)(bcol + r) * K_DIM + kbeg + (clog - 4) * 8;
    }

    f32x4 acc[4][4] = {};

    const int lr = lane & 15;
    const int hk = lane >> 4;
    const int xa = (hk ^ (lr & 7)) * 8;
    const int xb = xa ^ 32;

#define STAGE(buf, koff)                                                  \
    {                                                                     \
        _Pragma("unroll")                                                 \
        for (int i = 0; i < 4; ++i)                                       \
            load_lds16(src[i] + (koff), &sAB[(buf) * (BM * 64) + dstOff[i]]); \
    }

    STAGE(0, 0);
    __syncthreads();
    int cur = 0;

    for (int t = 0; t < NT; ++t) {
        if (t + 1 < NT) STAGE(cur ^ 1, (t + 1) * BK);

        f16x8 a[4], b[4];
#pragma unroll
        for (int m = 0; m < 4; ++m) {
            int r = wr * 64 + m * 16 + lr;
            a[m] = *(const f16x8*)&sAB[cur * (BM * 64) + r * 64 + xa];
        }
#pragma unroll
        for (int n = 0; n < 4; ++n) {
            int r = wc * 64 + n * 16 + lr;
            b[n] = *(const f16x8*)&sAB[cur * (BM * 64) + r * 64 + xb];
        }

#pragma unroll
        for (int m = 0; m < 4; ++m)
#pragma unroll
            for (int n = 0; n < 4; ++n)
                acc[m][n] = __builtin_amdgcn_mfma_f32_16x16x32_f16(a[m], b[n], acc[m][n], 0, 0, 0);

        __syncthreads();
        cur ^= 1;
    }

    // Epilogue: f16 partials (R10-validated). C/D: col=lane&15, row=(lane>>4)*4+j.
    _Float16* Pk = P + (size_t)ks * M_DIM * N_PAD;
#pragma unroll
    for (int m = 0; m < 4; ++m) {
        int r0 = brow + wr * 64 + m * 16 + hk * 4;
#pragma unroll
        for (int n = 0; n < 4; ++n) {
            int c = bcol + wc * 64 + n * 16 + lr;
#pragma unroll
            for (int j = 0; j < 4; ++j)
                Pk[(size_t)(r0 + j) * N_PAD + c] = (_Float16)acc[m][n][j];
        }
    }
#undef STAGE
}

__device__ inline void reduce_body(const _Float16* __restrict__ P,
                                   float* __restrict__ out,
                                   int gsize, int gidx) {
    const int n4out = (M_DIM * N_CLS) / 4;
    for (int i = gidx; i < n4out; i += gsize) {
        int flat = i * 4;
        int row = flat / N_CLS;
        int col = flat - row * N_CLS;
        size_t p = (size_t)row * N_PAD + col;
        f16x4 v0 = *(const f16x4*)&P[p];
        f16x4 v1 = *(const f16x4*)&P[(size_t)M_DIM * N_PAD + p];
        float4 r;
        r.x = (float)v0[0] + (float)v1[0];
        r.y = (float)v0[1] + (float)v1[1];
        r.z = (float)v0[2] + (float)v1[2];
        r.w = (float)v0[3] + (float)v1[3];
        *(float4*)&out[flat] = r;
    }
}

// ---------- fused cooperative kernel ----------
__launch_bounds__(256, 4)
__global__ void fused_kernel(const float* __restrict__ core,
                             const float* __restrict__ wts,
                             _Float16* __restrict__ A16,
                             _Float16* __restrict__ W16,
                             _Float16* __restrict__ P,
                             float* __restrict__ out) {
    __shared__ __align__(16) _Float16 sAB[2 * BM * 64];   // 32 KB
    cg::grid_group grid = cg::this_grid();

    const int gsize = gridDim.x * blockDim.x;
    const int gidx  = blockIdx.x * blockDim.x + threadIdx.x;

    // phase 1: fp32 -> f16 convert (all blocks)
    convert_body(core, wts, A16, W16, gsize, gidx);

    __threadfence();
    grid.sync();

    // phase 2: GEMM (blocks 0..511; others park at the next sync)
    if (blockIdx.x < GEMM_BLOCKS)
        gemm_body(A16, W16, P, sAB, blockIdx.x);

    __threadfence();
    grid.sync();

    // phase 3: reduce 2 f16 K-slices -> out (all blocks)
    reduce_body(P, out, gsize, gidx);
}

// ---------- standalone kernels (fallback path = proven R7 structure) ----------
__global__ void convert_f16(const float* __restrict__ core,
                            const float* __restrict__ wts,
                            _Float16* __restrict__ A16,
                            _Float16* __restrict__ W16) {
    convert_body(core, wts, A16, W16,
                 gridDim.x * blockDim.x, blockIdx.x * blockDim.x + threadIdx.x);
}

__launch_bounds__(256, 2)
__global__ void gemm_f16_kernel(const _Float16* __restrict__ A16,
                                const _Float16* __restrict__ W16,
                                _Float16* __restrict__ P) {
    __shared__ __align__(16) _Float16 sAB[2 * BM * 64];
    gemm_body(A16, W16, P, sAB, blockIdx.x);
}

__global__ void reduce_kernel(const _Float16* __restrict__ P,
                              float* __restrict__ out) {
    reduce_body(P, out,
                gridDim.x * blockDim.x, blockIdx.x * blockDim.x + threadIdx.x);
}

// ---------- fp32 fallback (only if ws too small) ----------
__global__ void fallback_gemm(const float* __restrict__ A, const float* __restrict__ W,
                              float* __restrict__ out) {
    __shared__ float sA[16][17];
    __shared__ float sW[16][17];
    int tx = threadIdx.x, ty = threadIdx.y;
    int row  = blockIdx.y * 16 + ty;
    int wrow = blockIdx.x * 16 + ty;
    float acc = 0.f;
    for (int k0 = 0; k0 < K_DIM; k0 += 16) {
        sA[ty][tx] = A[(size_t)row * K_DIM + k0 + tx];
        sW[ty][tx] = (wrow < N_CLS) ? W[(size_t)wrow * K_DIM + k0 + tx] : 0.f;
        __syncthreads();
#pragma unroll
        for (int kk = 0; kk < 16; ++kk) acc += sA[ty][kk] * sW[tx][kk];
        __syncthreads();
    }
    int col = blockIdx.x * 16 + tx;
    if (col < N_CLS) out[(size_t)row * N_CLS + col] = acc;
}

extern "C" void kernel_launch(void* const* d_in, const int* in_sizes, int n_in,
                              void* d_out, int out_size, void* d_ws, size_t ws_size,
                              hipStream_t stream) {
    const float* core    = (const float*)d_in[0];
    const float* weights = (const float*)d_in[1];
    float* out = (float*)d_out;

    const size_t need = (A_ELEMS + W_ELEMS + P_ELEMS) * sizeof(_Float16); // ~59 MiB
    if (ws_size < need) {
        dim3 blk(16, 16), grd((N_CLS + 15) / 16, M_DIM / 16);
        fallback_gemm<<<grd, blk, 0, stream>>>(core, weights, out);
        return;
    }

    _Float16* A16 = (_Float16*)d_ws;
    _Float16* W16 = A16 + A_ELEMS;
    _Float16* P   = W16 + W_ELEMS;

    void* args[] = {(void*)&core, (void*)&weights, (void*)&A16,
                    (void*)&W16, (void*)&P, (void*)&out};
    hipError_t err = hipLaunchCooperativeKernel(
        (const void*)fused_kernel, dim3(COOP_BLOCKS), dim3(256), args, 0, stream);

    if (err != hipSuccess) {
        // deterministic fallback: proven R7 3-kernel path (f16 partials)
        convert_f16<<<2048, 256, 0, stream>>>(core, weights, A16, W16);
        gemm_f16_kernel<<<GEMM_BLOCKS, 256, 0, stream>>>(A16, W16, P);
        reduce_kernel<<<(((M_DIM * N_CLS) / 4) + 255) / 256, 256, 0, stream>>>(P, out);
    }
}